// Round 10
// baseline (3990.028 us; speedup 1.0000x reference)
//
#include <hip/hip_runtime.h>
#include <math.h>

#define HD 64
#define DATT 16
#define NCIN 3
#define NCOUT 2
#define HH 24
#define WW 48
#define SS (HH*WW)          // 1152
#define NB 16
#define TSTEPS 37
#define INPUT_FRAMES 12

#define PR 26
#define PC 52
#define PHW (PR*PC)         // 1352

// ---------------- workspace layout (floats) ----------------
#define OFF_H     0                      // hA: post-LSTM h (packed split-bf16 ints, padded)
#define OFF_C     1384448
#define OFF_M     2564096
#define OFF_FEED  3743744                // packed ints
#define OFF_Z     3808640                // packed ints
#define ZERO_END  4154752                // zeroed each launch (1038688 f4)
#define OFF_QKV   4154752                // bf16 attention planes
#define OFF_MKV   5039488                // 64-float zero pad for K=32 upper half
#define OFF_HB    5629312                // hB: carry h (packed ints, padded), zero-init separately
#define OFF_IOG   8873344                // (unused now)
#define OFF_BF2   12412288               // gate-conv B fragments: 344064 ushort
#define OFF_BF    12596864               // out-conv B fragments: 282624 ushort
// end = 12738176 floats = 50.95 MB

typedef __attribute__((ext_vector_type(8))) short short8;
typedef __attribute__((ext_vector_type(4))) float f32x4;

__device__ __forceinline__ float sigmoidf_(float x) {
    return 1.0f / (1.0f + __expf(-x));
}
__device__ __forceinline__ unsigned short f2bf(float f) {
    unsigned u = __float_as_uint(f);
    unsigned r = (u + 0x7fffu + ((u >> 16) & 1u)) >> 16;
    return (unsigned short)r;
}
__device__ __forceinline__ float bf2f(unsigned short b) {
    return __uint_as_float(((unsigned)b) << 16);
}
// packed split-bf16: low16 = hi bf16, high16 = lo bf16 (value ~= hi + lo)
__device__ __forceinline__ unsigned packbf(float f) {
    unsigned short hi = f2bf(f);
    unsigned short lo = f2bf(f - bf2f(hi));
    return ((unsigned)lo << 16) | (unsigned)hi;
}
__device__ __forceinline__ float unpackbf(unsigned pk) {
    return __uint_as_float(pk << 16) + __uint_as_float(pk & 0xffff0000u);
}
__device__ __forceinline__ unsigned cvt_pk_bf16(float a, float b) {
    unsigned r;
    asm("v_cvt_pk_bf16_f32 %0, %1, %2" : "=v"(r) : "v"(a), "v"(b));
    return r;
}
// Row permutation for attention K planes (PV A-fragment order)
__device__ __forceinline__ int permrow(int t) {
    int kb = t >> 5, tl = t & 31;
    int quad = tl >> 3, rr = tl & 7;
    return kb * 32 + ((rr >= 4) ? 16 : 0) + quad * 4 + (rr & 3);
}

// build hi/lo bf16 A-fragments from 8 packed ints (2x int4)
#define MKFRAG(P0, P1, ah, al) do {                                  \
    ah.i[0] = (P0.y << 16) | (P0.x & 0xffff);                        \
    ah.i[1] = (P0.w << 16) | (P0.z & 0xffff);                        \
    ah.i[2] = (P1.y << 16) | (P1.x & 0xffff);                        \
    ah.i[3] = (P1.w << 16) | (P1.z & 0xffff);                        \
    al.i[0] = (P0.y & 0xffff0000) | ((unsigned)P0.x >> 16);          \
    al.i[1] = (P0.w & 0xffff0000) | ((unsigned)P0.z >> 16);          \
    al.i[2] = (P1.y & 0xffff0000) | ((unsigned)P1.x >> 16);          \
    al.i[3] = (P1.w & 0xffff0000) | ((unsigned)P1.z >> 16);          \
} while (0)

__global__ void k_zero(float* __restrict__ p, int n4) {
    int i = blockIdx.x * blockDim.x + threadIdx.x;
    if (i < n4) ((float4*)p)[i] = make_float4(0.f, 0.f, 0.f, 0.f);
}

// ---- B fragment prep for MFMA gate conv ----
__global__ void k_prep_bf2(const float* __restrict__ cw, unsigned short* __restrict__ bbuf) {
    int idx = blockIdx.x * 256 + threadIdx.x;
    if (idx >= 344064) return;
    int j    = idx & 7;
    int lane = (idx >> 3) & 63;
    int ki   = (idx >> 9) % 21;
    int nt   = (idx / 10752) % 16;
    int p    = idx / 172032;
    int k = ki * 32 + (lane >> 4) * 8 + j;
    int ncol = nt * 16 + (lane & 15);
    unsigned short v = 0;
    if (k < 648) {
        int c = k % 72, kt = k / 72;
        if (c < 67) {
            float w = cw[ncol * 603 + c * 9 + kt];
            unsigned short hi = f2bf(w);
            v = (p == 0) ? hi : f2bf(w - bf2f(hi));
        }
    }
    bbuf[idx] = v;
}

// ---- B fragment prep for MFMA out conv ----
__global__ void k_prep_bf(const float* __restrict__ ow, unsigned short* __restrict__ bbuf) {
    int idx = blockIdx.x * 256 + threadIdx.x;
    if (idx >= 282624) return;
    int j    = idx & 7;
    int lane = (idx >> 3) & 63;
    int ki   = (idx >> 9) % 23;
    int nt   = (idx / 11776) % 12;
    int p    = idx / 141312;
    int k = ki * 32 + (lane >> 4) * 8 + j;
    int ncol = nt * 16 + (lane & 15);
    unsigned short v = 0;
    if (k < 720) {
        int c = k % 80, kt = k / 80;
        float w = ow[ncol * 720 + c * 9 + kt];
        unsigned short hi = f2bf(w);
        v = (p == 0) ? hi : f2bf(w - bf2f(hi));
    }
    bbuf[idx] = v;
}

// ---------------- initial feed (t=0), packed ----------------
__global__ void k_feed0(const float* __restrict__ x, unsigned* __restrict__ feed) {
    int i = blockIdx.x * blockDim.x + threadIdx.x;
    if (i >= NB * 3 * SS) return;
    int s = i % SS;
    int ch = (i / SS) % 3;
    int n = i / (3 * SS);
    int y = s / WW, xx = s % WW;
    float v = x[(((size_t)(n * TSTEPS + 0) * HH + y) * WW + xx) * NCIN + ch];
    feed[((size_t)(n * 3 + ch) * PR + (y + 1)) * PC + (xx + 1)] = packbf(v);
}

// ---------------- MFMA gate conv + FUSED LSTM gates (split-K waves) ----------
// grid (24 y, 2 nb, 16 n); block 512 = 8 waves = (2 K-halves x 4 gates).
// Measured 42.9 us in R9 (vs 44.1 for the 4-wave variant). Halves merged
// through the LDS gate exchange (48 frags).
#define ASTR2 76
#define ZOFF2 (3*52*ASTR2)
__global__ __launch_bounds__(512) void k_conv_lstm_mfma(
    const unsigned* __restrict__ feed, const unsigned* __restrict__ hin,
    const unsigned short* __restrict__ bbuf, const float* __restrict__ cb,
    float* __restrict__ c, unsigned* __restrict__ hout)
{
    __shared__ __align__(16) int lds[13064];   // max(A-tile 11864, exch 48*272=13056)
    const int y0 = blockIdx.x;
    const int nb = blockIdx.y;
    const int n  = blockIdx.z;
    const int tid = threadIdx.x;

    // ---- epilogue prefetch (addresses known at entry) ----
    const int ech = tid & 31;
    const int exg = tid >> 5;                    // 0..15 -> 3 x-positions each
    const int egch = nb * 32 + ech;
    const size_t ecbase = ((size_t)(n * HD + egch) * HH + y0) * WW + exg * 3;
    float cpre[3];
#pragma unroll
    for (int k = 0; k < 3; ++k) cpre[k] = c[ecbase + k];
    const float ebi = cb[egch], ebf = cb[64 + egch];
    const float ebo = cb[128 + egch], ebg = cb[192 + egch];

    const unsigned* fbase = feed + (size_t)n * 3 * PHW;
    const unsigned* hbase = hin + (size_t)n * HD * PHW;
    for (int e = tid; e < 2808; e += 512) {
        int grp = e / 156;
        int r2  = e - grp * 156;
        int pr = r2 / 52, pc = r2 - pr * 52;
        int cc0 = grp * 4;
        int vv[4];
#pragma unroll
        for (int j = 0; j < 4; ++j) {
            int cc = cc0 + j;
            int t = 0;
            if (cc < 3)        t = (int)fbase[(size_t)cc * PHW + (y0 + pr) * PC + pc];
            else if (cc < 67)  t = (int)hbase[(size_t)(cc - 3) * PHW + (y0 + pr) * PC + pc];
            vv[j] = t;
        }
        int4 v; v.x = vv[0]; v.y = vv[1]; v.z = vv[2]; v.w = vv[3];
        *(int4*)&lds[r2 * ASTR2 + cc0] = v;
    }
    if (tid < 8) lds[ZOFF2 + tid] = 0;
    __syncthreads();

    const int wv = tid >> 6;          // 0..7
    const int half = wv >> 2;         // K-half
    const int gate = wv & 3;
    const int lane = tid & 63;
    const int mcol = lane & 15;
    const int quad = lane >> 4;

    f32x4 acc[2][3];
#pragma unroll
    for (int jg = 0; jg < 2; ++jg)
#pragma unroll
        for (int xt = 0; xt < 3; ++xt) acc[jg][xt] = (f32x4){0.f, 0.f, 0.f, 0.f};

    const unsigned short* b0 = bbuf + ((size_t)(gate * 4 + nb * 2 + 0) * 21) * 512 + lane * 8;
    const unsigned short* b1 = bbuf + ((size_t)(gate * 4 + nb * 2 + 1) * 21) * 512 + lane * 8;

    const int ki0 = half ? 11 : 0;
    const int ki1 = half ? 21 : 11;

    short8 cb0h = *(const short8*)(b0 + ki0 * 512);
    short8 cb0l = *(const short8*)(b0 + ki0 * 512 + 172032);
    short8 cb1h = *(const short8*)(b1 + ki0 * 512);
    short8 cb1l = *(const short8*)(b1 + ki0 * 512 + 172032);

    for (int ki = ki0; ki < ki1; ++ki) {
        int kn = (ki + 1 < ki1) ? (ki + 1) * 512 : ki * 512;
        short8 nb0h = *(const short8*)(b0 + kn);
        short8 nb0l = *(const short8*)(b0 + kn + 172032);
        short8 nb1h = *(const short8*)(b1 + kn);
        short8 nb1l = *(const short8*)(b1 + kn + 172032);

        int k0 = ki * 32 + quad * 8;
        int ab, step;
        if (k0 < 648) {
            int kt = k0 / 72;
            int c0 = k0 - kt * 72;
            int dy = kt / 3, dx = kt - dy * 3;
            ab = (dy * 52 + mcol + dx) * ASTR2 + c0;
            step = 16 * ASTR2;
        } else {
            ab = ZOFF2; step = 0;
        }
        int4 A0 = *(const int4*)&lds[ab],            A1 = *(const int4*)&lds[ab + 4];
        int4 B0 = *(const int4*)&lds[ab + step],     B1 = *(const int4*)&lds[ab + step + 4];
        int4 C0 = *(const int4*)&lds[ab + 2 * step], C1 = *(const int4*)&lds[ab + 2 * step + 4];

        union { int i[4]; short8 v; } ah, al;
        MKFRAG(A0, A1, ah, al);
        acc[0][0] = __builtin_amdgcn_mfma_f32_16x16x32_bf16(ah.v, cb0h, acc[0][0], 0, 0, 0);
        acc[0][0] = __builtin_amdgcn_mfma_f32_16x16x32_bf16(ah.v, cb0l, acc[0][0], 0, 0, 0);
        acc[0][0] = __builtin_amdgcn_mfma_f32_16x16x32_bf16(al.v, cb0h, acc[0][0], 0, 0, 0);
        acc[1][0] = __builtin_amdgcn_mfma_f32_16x16x32_bf16(ah.v, cb1h, acc[1][0], 0, 0, 0);
        acc[1][0] = __builtin_amdgcn_mfma_f32_16x16x32_bf16(ah.v, cb1l, acc[1][0], 0, 0, 0);
        acc[1][0] = __builtin_amdgcn_mfma_f32_16x16x32_bf16(al.v, cb1h, acc[1][0], 0, 0, 0);
        MKFRAG(B0, B1, ah, al);
        acc[0][1] = __builtin_amdgcn_mfma_f32_16x16x32_bf16(ah.v, cb0h, acc[0][1], 0, 0, 0);
        acc[0][1] = __builtin_amdgcn_mfma_f32_16x16x32_bf16(ah.v, cb0l, acc[0][1], 0, 0, 0);
        acc[0][1] = __builtin_amdgcn_mfma_f32_16x16x32_bf16(al.v, cb0h, acc[0][1], 0, 0, 0);
        acc[1][1] = __builtin_amdgcn_mfma_f32_16x16x32_bf16(ah.v, cb1h, acc[1][1], 0, 0, 0);
        acc[1][1] = __builtin_amdgcn_mfma_f32_16x16x32_bf16(ah.v, cb1l, acc[1][1], 0, 0, 0);
        acc[1][1] = __builtin_amdgcn_mfma_f32_16x16x32_bf16(al.v, cb1h, acc[1][1], 0, 0, 0);
        MKFRAG(C0, C1, ah, al);
        acc[0][2] = __builtin_amdgcn_mfma_f32_16x16x32_bf16(ah.v, cb0h, acc[0][2], 0, 0, 0);
        acc[0][2] = __builtin_amdgcn_mfma_f32_16x16x32_bf16(ah.v, cb0l, acc[0][2], 0, 0, 0);
        acc[0][2] = __builtin_amdgcn_mfma_f32_16x16x32_bf16(al.v, cb0h, acc[0][2], 0, 0, 0);
        acc[1][2] = __builtin_amdgcn_mfma_f32_16x16x32_bf16(ah.v, cb1h, acc[1][2], 0, 0, 0);
        acc[1][2] = __builtin_amdgcn_mfma_f32_16x16x32_bf16(ah.v, cb1l, acc[1][2], 0, 0, 0);
        acc[1][2] = __builtin_amdgcn_mfma_f32_16x16x32_bf16(al.v, cb1h, acc[1][2], 0, 0, 0);

        cb0h = nb0h; cb0l = nb0l; cb1h = nb1h; cb1l = nb1l;
    }

    // ---- cross-wave gate exchange: 48 frags (2 halves x 4 gates x 2 jg x 3 xt) ----
    __syncthreads();
    float* exch = (float*)lds;
#pragma unroll
    for (int jg = 0; jg < 2; ++jg)
#pragma unroll
        for (int xt = 0; xt < 3; ++xt)
#pragma unroll
            for (int r = 0; r < 4; ++r)
                exch[(((half * 4 + gate) * 2 + jg) * 3 + xt) * 272 + (quad * 4 + r) * 17 + mcol]
                    = acc[jg][xt][r];
    __syncthreads();

    // epilogue: 32 channels x 48 x; thread = (ech, exg), 3 x each; sum halves
    const int jg = ech >> 4, col = ech & 15;
    unsigned* hp = hout + ((size_t)(n * HD + egch) * PR + y0 + 1) * PC + 1;
#define EXL(hf, g) exch[((((hf) * 4 + (g)) * 2 + jg) * 3 + xt) * 272 + row * 17 + col]
#pragma unroll
    for (int k = 0; k < 3; ++k) {
        int x = exg * 3 + k;
        int xt = x >> 4, row = x & 15;
        float iv = sigmoidf_(EXL(0, 0) + EXL(1, 0) + ebi);
        float fv = sigmoidf_(EXL(0, 1) + EXL(1, 1) + ebf);
        float ov = sigmoidf_(EXL(0, 2) + EXL(1, 2) + ebo);
        float gv = tanhf    (EXL(0, 3) + EXL(1, 3) + ebg);
        float cn = fv * cpre[k] + iv * gv;
        float hn = ov * tanhf(cn);
        c[ecbase + k] = cn;
        hp[x] = packbf(hn);
    }
#undef EXL
}

// ---------------- MFMA out conv + FUSED SA gates (R8 champion version) ----------------
// grid (24 y, 2 cb, 16 n); block 192 = 3 waves, wave = GATE (si/sg/so).
#define ASTR (84)
#define ZOFF (3*52*ASTR)
__global__ __launch_bounds__(192) void k_conv_sa(
    const unsigned* __restrict__ Zin, const unsigned* __restrict__ hin,
    const unsigned short* __restrict__ bbuf, const float* __restrict__ ob,
    float* __restrict__ m, unsigned* __restrict__ hout)
{
    __shared__ __align__(16) int lds[3 * 52 * ASTR + 8];
    const int y0 = blockIdx.x;
    const int cbk = blockIdx.y;
    const int n  = blockIdx.z;
    const int tid = threadIdx.x;

    // ---- epilogue prefetch ----
    const int ech = tid & 31;
    const int exg = tid >> 5;                    // 0..5
    const int egch = cbk * 32 + ech;
    float* emrow = m + ((size_t)(n * HD + egch) * HH + y0) * WW;
    float mpre[8];
    {
        float4 a = *(const float4*)&emrow[exg * 8];
        float4 b = *(const float4*)&emrow[exg * 8 + 4];
        mpre[0] = a.x; mpre[1] = a.y; mpre[2] = a.z; mpre[3] = a.w;
        mpre[4] = b.x; mpre[5] = b.y; mpre[6] = b.z; mpre[7] = b.w;
    }
    const float ebsi = ob[egch], ebsg = ob[64 + egch], ebso = ob[128 + egch];

    const unsigned* zbase = Zin + (size_t)n * DATT * PHW;
    const unsigned* hbase = hin + (size_t)n * HD * PHW;
    for (int e = tid; e < 3120; e += 192) {   // 20 quads x 156 spatial
        int grp = e / 156;
        int r2  = e - grp * 156;
        int pr = r2 / 52, pc = r2 - pr * 52;
        int cc0 = grp * 4;
        int vv[4];
#pragma unroll
        for (int j = 0; j < 4; ++j) {
            int cc = cc0 + j;
            const unsigned* src = (cc < 16) ? (zbase + (size_t)cc * PHW)
                                            : (hbase + (size_t)(cc - 16) * PHW);
            vv[j] = (int)src[(y0 + pr) * PC + pc];
        }
        int4 v; v.x = vv[0]; v.y = vv[1]; v.z = vv[2]; v.w = vv[3];
        *(int4*)&lds[r2 * ASTR + cc0] = v;
    }
    if (tid < 8) lds[ZOFF + tid] = 0;
    __syncthreads();

    const int wv = tid >> 6;          // wave = gate 0..2 (si/sg/so)
    const int lane = tid & 63;
    const int mcol = lane & 15;
    const int quad = lane >> 4;

    f32x4 acc[2][3];
#pragma unroll
    for (int j = 0; j < 2; ++j)
#pragma unroll
        for (int xt = 0; xt < 3; ++xt) acc[j][xt] = (f32x4){0.f, 0.f, 0.f, 0.f};

    const unsigned short* b0 = bbuf + ((size_t)(wv * 4 + cbk * 2 + 0) * 23) * 512 + lane * 8;
    const unsigned short* b1 = bbuf + ((size_t)(wv * 4 + cbk * 2 + 1) * 23) * 512 + lane * 8;

    short8 cb0h = *(const short8*)(b0);
    short8 cb0l = *(const short8*)(b0 + 141312);
    short8 cb1h = *(const short8*)(b1);
    short8 cb1l = *(const short8*)(b1 + 141312);

    for (int ki = 0; ki < 23; ++ki) {
        int kn = (ki < 22) ? (ki + 1) * 512 : 22 * 512;
        short8 nb0h = *(const short8*)(b0 + kn);
        short8 nb0l = *(const short8*)(b0 + kn + 141312);
        short8 nb1h = *(const short8*)(b1 + kn);
        short8 nb1l = *(const short8*)(b1 + kn + 141312);

        int k0 = ki * 32 + quad * 8;
        int ab, step;
        if (k0 < 720) {
            int kt = k0 / 80;
            int c0 = k0 - kt * 80;
            int dy = kt / 3, dx = kt - dy * 3;
            ab = (dy * 52 + mcol + dx) * ASTR + c0;
            step = 16 * ASTR;
        } else {
            ab = ZOFF; step = 0;
        }
        int4 A0 = *(const int4*)&lds[ab],            A1 = *(const int4*)&lds[ab + 4];
        int4 B0 = *(const int4*)&lds[ab + step],     B1 = *(const int4*)&lds[ab + step + 4];
        int4 C0 = *(const int4*)&lds[ab + 2 * step], C1 = *(const int4*)&lds[ab + 2 * step + 4];

        union { int i[4]; short8 v; } ah, al;
        MKFRAG(A0, A1, ah, al);
        acc[0][0] = __builtin_amdgcn_mfma_f32_16x16x32_bf16(ah.v, cb0h, acc[0][0], 0, 0, 0);
        acc[0][0] = __builtin_amdgcn_mfma_f32_16x16x32_bf16(ah.v, cb0l, acc[0][0], 0, 0, 0);
        acc[0][0] = __builtin_amdgcn_mfma_f32_16x16x32_bf16(al.v, cb0h, acc[0][0], 0, 0, 0);
        acc[1][0] = __builtin_amdgcn_mfma_f32_16x16x32_bf16(ah.v, cb1h, acc[1][0], 0, 0, 0);
        acc[1][0] = __builtin_amdgcn_mfma_f32_16x16x32_bf16(ah.v, cb1l, acc[1][0], 0, 0, 0);
        acc[1][0] = __builtin_amdgcn_mfma_f32_16x16x32_bf16(al.v, cb1h, acc[1][0], 0, 0, 0);
        MKFRAG(B0, B1, ah, al);
        acc[0][1] = __builtin_amdgcn_mfma_f32_16x16x32_bf16(ah.v, cb0h, acc[0][1], 0, 0, 0);
        acc[0][1] = __builtin_amdgcn_mfma_f32_16x16x32_bf16(ah.v, cb0l, acc[0][1], 0, 0, 0);
        acc[0][1] = __builtin_amdgcn_mfma_f32_16x16x32_bf16(al.v, cb0h, acc[0][1], 0, 0, 0);
        acc[1][1] = __builtin_amdgcn_mfma_f32_16x16x32_bf16(ah.v, cb1h, acc[1][1], 0, 0, 0);
        acc[1][1] = __builtin_amdgcn_mfma_f32_16x16x32_bf16(ah.v, cb1l, acc[1][1], 0, 0, 0);
        acc[1][1] = __builtin_amdgcn_mfma_f32_16x16x32_bf16(al.v, cb1h, acc[1][1], 0, 0, 0);
        MKFRAG(C0, C1, ah, al);
        acc[0][2] = __builtin_amdgcn_mfma_f32_16x16x32_bf16(ah.v, cb0h, acc[0][2], 0, 0, 0);
        acc[0][2] = __builtin_amdgcn_mfma_f32_16x16x32_bf16(ah.v, cb0l, acc[0][2], 0, 0, 0);
        acc[0][2] = __builtin_amdgcn_mfma_f32_16x16x32_bf16(al.v, cb0h, acc[0][2], 0, 0, 0);
        acc[1][2] = __builtin_amdgcn_mfma_f32_16x16x32_bf16(ah.v, cb1h, acc[1][2], 0, 0, 0);
        acc[1][2] = __builtin_amdgcn_mfma_f32_16x16x32_bf16(ah.v, cb1l, acc[1][2], 0, 0, 0);
        acc[1][2] = __builtin_amdgcn_mfma_f32_16x16x32_bf16(al.v, cb1h, acc[1][2], 0, 0, 0);

        cb0h = nb0h; cb0l = nb0l; cb1h = nb1h; cb1l = nb1l;
    }

    // ---- cross-wave gate exchange ----
    __syncthreads();
    float* exch = (float*)lds;        // [frag=(gate*2+j)*3+xt][row16 x str17][col]
#pragma unroll
    for (int j = 0; j < 2; ++j)
#pragma unroll
        for (int xt = 0; xt < 3; ++xt)
#pragma unroll
            for (int r = 0; r < 4; ++r)
                exch[((wv * 2 + j) * 3 + xt) * 272 + (quad * 4 + r) * 17 + mcol] = acc[j][xt][r];
    __syncthreads();

    // fused SA-gate epilogue: thread = (ech, exg in 0..5), 8 x each
    const int jg = ech >> 4, col = ech & 15;
    unsigned* hp = hout + ((size_t)(n * HD + egch) * PR + y0 + 1) * PC + 1;
#pragma unroll
    for (int k = 0; k < 8; ++k) {
        int x = exg * 8 + k;
        int xt = x >> 4, row = x & 15;
        float si = sigmoidf_(exch[((0 * 2 + jg) * 3 + xt) * 272 + row * 17 + col] + ebsi);
        float sg = tanhf    (exch[((1 * 2 + jg) * 3 + xt) * 272 + row * 17 + col] + ebsg);
        float so =           exch[((2 * 2 + jg) * 3 + xt) * 272 + row * 17 + col] + ebso;
        float mn = si * sg + (1.f - si) * mpre[k];
        emrow[x] = mn;
        hp[x] = packbf(sigmoidf_(so) * mn);
    }
}

// ---------------- 1x1 q/k/v + mk/mv projections -> bf16 MFMA planes ----------------
__global__ __launch_bounds__(256) void k_qkv(
    const unsigned* __restrict__ h, const float* __restrict__ m,
    const float* __restrict__ hw, const float* __restrict__ hb,
    const float* __restrict__ mw, const float* __restrict__ mb,
    unsigned short* __restrict__ pl) {
    __shared__ float lw[512];
    __shared__ float lb[8];
    const int g = blockIdx.y;
    const int tid = threadIdx.x;
    const float* wsrc = (g < 6) ? (hw + g * 512) : (mw + (g - 6) * 512);
    const float* bsrc = (g < 6) ? (hb + g * 8) : (mb + (g - 6) * 8);
    for (int i = tid; i < 512; i += 256) lw[i] = wsrc[i];
    if (tid < 8) lb[tid] = bsrc[tid];
    __syncthreads();

    int idx = blockIdx.x * 256 + tid;
    int s = idx % SS;
    int n = idx / SS;

    float reg[HD];
    if (g < 6) {
        int y = s / WW, x = s % WW;
        const unsigned* src = h + (size_t)n * HD * PHW + (y + 1) * PC + (x + 1);
#pragma unroll
        for (int ic = 0; ic < HD; ++ic) reg[ic] = unpackbf(src[ic * PHW]);
    } else {
        const float* src = m + (size_t)n * HD * SS + s;
#pragma unroll
        for (int ic = 0; ic < HD; ++ic) reg[ic] = src[ic * SS];
    }

    float out[8];
#pragma unroll
    for (int j = 0; j < 8; ++j) {
        const float* wr = &lw[j * HD];
        float a = lb[j];
#pragma unroll
        for (int ic = 0; ic < HD; ++ic) a += reg[ic] * wr[ic];
        out[j] = a;
    }

    unsigned short* bq  = pl;
    unsigned short* akh = pl + 294912;
    unsigned short* akm = pl + 589824;
    unsigned short* bvh = pl + 884736;
    unsigned short* bvm = pl + 1179648;
    const int c0 = (g & 1) * 8;

    if (g < 2) {                       // Q: [n][s][16]
        unsigned w0 = (unsigned)f2bf(out[0]) | ((unsigned)f2bf(out[1]) << 16);
        unsigned w1 = (unsigned)f2bf(out[2]) | ((unsigned)f2bf(out[3]) << 16);
        unsigned w2 = (unsigned)f2bf(out[4]) | ((unsigned)f2bf(out[5]) << 16);
        unsigned w3 = (unsigned)f2bf(out[6]) | ((unsigned)f2bf(out[7]) << 16);
        *(uint4*)&bq[((size_t)n * SS + s) * 16 + c0] = make_uint4(w0, w1, w2, w3);
    } else if (g < 4 || (g >= 6 && g < 8)) {   // K planes, permuted rows
        int row = permrow(s);
        unsigned short* base = (g < 4) ? akh : akm;
        unsigned w0 = (unsigned)f2bf(out[0]) | ((unsigned)f2bf(out[1]) << 16);
        unsigned w1 = (unsigned)f2bf(out[2]) | ((unsigned)f2bf(out[3]) << 16);
        unsigned w2 = (unsigned)f2bf(out[4]) | ((unsigned)f2bf(out[5]) << 16);
        unsigned w3 = (unsigned)f2bf(out[6]) | ((unsigned)f2bf(out[7]) << 16);
        *(uint4*)&base[((size_t)n * SS + row) * 16 + c0] = make_uint4(w0, w1, w2, w3);
    } else {                            // V planes, transposed [n][d][1152]
        unsigned short* base = (g < 6) ? bvh : bvm;
#pragma unroll
        for (int j = 0; j < 8; ++j)
            base[((size_t)n * 16 + c0 + j) * SS + s] = f2bf(out[j]);
    }
}

// ---------------- MFMA dual spatial attention + z 1x1 ----------------
__global__ __launch_bounds__(256) void k_attn(
    const unsigned short* __restrict__ pl, const unsigned short* __restrict__ zbuf,
    const float* __restrict__ zw, const float* __restrict__ zb,
    unsigned* __restrict__ Z)
{
    __shared__ float ldsO[4][2][16][16];
    __shared__ float ldsF[2][16][16];
    __shared__ float ldsL[4][2][16];
    __shared__ float ldsLF[2][16];

    const int n   = blockIdx.x;
    const int qt  = blockIdx.y;
    const int tid = threadIdx.x;
    const int wv  = tid >> 6;
    const int lane = tid & 63;
    const int col  = lane & 15;
    const int quad = lane >> 4;
    const bool hi  = quad >= 2;          // K=32 upper half -> zeros

    const unsigned short* bq  = pl;
    const unsigned short* akh = pl + 294912;
    const unsigned short* akm = pl + 589824;
    const unsigned short* bvh = pl + 884736;
    const unsigned short* bvm = pl + 1179648;

    const size_t nb = (size_t)n * 18432;
    const int stepk = hi ? 0 : 512;
    const int subk  = hi ? 0 : 256;
    const unsigned short* qp  = hi ? zbuf : (bq  + nb + ((size_t)(qt * 16 + col)) * 16 + quad * 8);
    const unsigned short* khb = hi ? zbuf : (akh + nb + col * 16 + quad * 8);
    const unsigned short* kmb = hi ? zbuf : (akm + nb + col * 16 + quad * 8);
    const unsigned short* vhb = bvh + nb + (size_t)col * SS + quad * 8;
    const unsigned short* vmb = bvm + nb + (size_t)col * SS + quad * 8;

    short8 qf = *(const short8*)qp;

    f32x4 oh = (f32x4){0.f,0.f,0.f,0.f}, om = (f32x4){0.f,0.f,0.f,0.f};
    float lh = 0.f, lm = 0.f;
    const int kb0 = wv * 9, kb1 = kb0 + 9;
    for (int kb = kb0; kb < kb1; ++kb) {
        const unsigned short* kh0 = khb + (size_t)kb * stepk;
        const unsigned short* km0 = kmb + (size_t)kb * stepk;
        short8 khA = *(const short8*)kh0;
        short8 khB = *(const short8*)(kh0 + subk);
        short8 kmA = *(const short8*)km0;
        short8 kmB = *(const short8*)(km0 + subk);
        short8 vh  = *(const short8*)(vhb + (size_t)kb * 32);
        short8 vm  = *(const short8*)(vmb + (size_t)kb * 32);
        const f32x4 z4 = (f32x4){0.f,0.f,0.f,0.f};
        f32x4 sA = __builtin_amdgcn_mfma_f32_16x16x32_bf16(khA, qf, z4, 0, 0, 0);
        f32x4 sB = __builtin_amdgcn_mfma_f32_16x16x32_bf16(khB, qf, z4, 0, 0, 0);
        f32x4 tA = __builtin_amdgcn_mfma_f32_16x16x32_bf16(kmA, qf, z4, 0, 0, 0);
        f32x4 tB = __builtin_amdgcn_mfma_f32_16x16x32_bf16(kmB, qf, z4, 0, 0, 0);

        float pa0 = __expf(0.25f * sA[0]), pa1 = __expf(0.25f * sA[1]);
        float pa2 = __expf(0.25f * sA[2]), pa3 = __expf(0.25f * sA[3]);
        float pb0 = __expf(0.25f * sB[0]), pb1 = __expf(0.25f * sB[1]);
        float pb2 = __expf(0.25f * sB[2]), pb3 = __expf(0.25f * sB[3]);
        lh += (pa0 + pa1 + pa2 + pa3) + (pb0 + pb1 + pb2 + pb3);
        union { unsigned u[4]; short8 v; } ph;
        ph.u[0] = cvt_pk_bf16(pa0, pa1); ph.u[1] = cvt_pk_bf16(pa2, pa3);
        ph.u[2] = cvt_pk_bf16(pb0, pb1); ph.u[3] = cvt_pk_bf16(pb2, pb3);
        oh = __builtin_amdgcn_mfma_f32_16x16x32_bf16(ph.v, vh, oh, 0, 0, 0);

        float qa0 = __expf(0.25f * tA[0]), qa1 = __expf(0.25f * tA[1]);
        float qa2 = __expf(0.25f * tA[2]), qa3 = __expf(0.25f * tA[3]);
        float qb0 = __expf(0.25f * tB[0]), qb1 = __expf(0.25f * tB[1]);
        float qb2 = __expf(0.25f * tB[2]), qb3 = __expf(0.25f * tB[3]);
        lm += (qa0 + qa1 + qa2 + qa3) + (qb0 + qb1 + qb2 + qb3);
        union { unsigned u[4]; short8 v; } pm;
        pm.u[0] = cvt_pk_bf16(qa0, qa1); pm.u[1] = cvt_pk_bf16(qa2, qa3);
        pm.u[2] = cvt_pk_bf16(qb0, qb1); pm.u[3] = cvt_pk_bf16(qb2, qb3);
        om = __builtin_amdgcn_mfma_f32_16x16x32_bf16(pm.v, vm, om, 0, 0, 0);
    }

    lh += __shfl_xor(lh, 16); lh += __shfl_xor(lh, 32);
    lm += __shfl_xor(lm, 16); lm += __shfl_xor(lm, 32);

#pragma unroll
    for (int r = 0; r < 4; ++r) {
        ldsO[wv][0][quad * 4 + r][col] = oh[r];
        ldsO[wv][1][quad * 4 + r][col] = om[r];
    }
    if (lane < 16) { ldsL[wv][0][lane] = lh; ldsL[wv][1][lane] = lm; }
    __syncthreads();

    if (tid < 128) {
        int a_ = tid >> 6, rem = tid & 63, q_ = rem >> 2, j4 = (rem & 3) * 4;
        float4 s4 = make_float4(0.f, 0.f, 0.f, 0.f);
#pragma unroll
        for (int w = 0; w < 4; ++w) {
            float4 v = *(const float4*)&ldsO[w][a_][q_][j4];
            s4.x += v.x; s4.y += v.y; s4.z += v.z; s4.w += v.w;
        }
        *(float4*)&ldsF[a_][q_][j4] = s4;
    } else if (tid < 160) {
        int e = tid - 128, a_ = e >> 4, q_ = e & 15;
        ldsLF[a_][q_] = ldsL[0][a_][q_] + ldsL[1][a_][q_] +
                        ldsL[2][a_][q_] + ldsL[3][a_][q_];
    }
    __syncthreads();

    const int q  = tid & 15;
    const int zc = tid >> 4;
    float iLh = 1.f / ldsLF[0][q], iLm = 1.f / ldsLF[1][q];
    const float* zr = zw + zc * 32;
    float a = zb[zc];
#pragma unroll
    for (int j = 0; j < 16; ++j)
        a += zr[j] * (ldsF[0][q][j] * iLh) + zr[16 + j] * (ldsF[1][q][j] * iLm);
    int s = qt * 16 + q;
    int y = s / WW, x = s % WW;
    Z[((size_t)(n * DATT + zc) * PR + y + 1) * PC + x + 1] = packbf(a);
}

// ---------------- out 1x1 (64->2) + next-step feed (packed), fused ----------------
// 288 blocks; each spatial point handled by 4 lanes (16 ic each) + shfl reduce.
__global__ __launch_bounds__(256) void k_out_feed(
    const unsigned* __restrict__ h, const float* __restrict__ ow,
    const float* __restrict__ ob, const float* __restrict__ x,
    float* __restrict__ outbuf, unsigned* __restrict__ feed, int t) {
    const int tid = threadIdx.x;
    const int lane = tid & 63;
    const int wv = tid >> 6;
    const int part = lane >> 4;     // 0..3 -> ic group
    const int sl = lane & 15;
    int sidx = blockIdx.x * 64 + wv * 16 + sl;   // 0..18431
    int s = sidx % SS;
    int n = sidx / SS;
    int y = s / WW, xx = s % WW;
    const unsigned* src = h + (size_t)n * HD * PHW + (y + 1) * PC + (xx + 1);
    float o0 = 0.f, o1 = 0.f;
#pragma unroll
    for (int i = 0; i < 16; ++i) {
        int ic = part * 16 + i;
        float r = unpackbf(src[ic * PHW]);
        o0 += r * ow[ic];
        o1 += r * ow[HD + ic];
    }
    o0 += __shfl_xor(o0, 16); o0 += __shfl_xor(o0, 32);
    o1 += __shfl_xor(o1, 16); o1 += __shfl_xor(o1, 32);

    if (part == 0) {
        o0 += ob[0]; o1 += ob[1];
        outbuf[(((size_t)n * TSTEPS + t) * NCOUT + 0) * SS + s] = o0;
        outbuf[(((size_t)n * TSTEPS + t) * NCOUT + 1) * SS + s] = o1;
        if (t + 1 < TSTEPS) {
            int t1 = t + 1;
            const float* xp = &x[(((size_t)(n * TSTEPS + t1) * HH + y) * WW + xx) * NCIN];
            float f0, f1, f2 = xp[2];
            if (t1 < INPUT_FRAMES) { f0 = xp[0]; f1 = xp[1]; }
            else { f0 = o0; f1 = o1; }
            size_t fb = ((size_t)(n * 3 + 0) * PR + y + 1) * PC + xx + 1;
            feed[fb] = packbf(f0);
            feed[fb + PHW] = packbf(f1);
            feed[fb + 2 * (size_t)PHW] = packbf(f2);
        }
    }
}

// ---------------- nino prediction ----------------
__global__ void k_nino(const float* __restrict__ outbuf, float* __restrict__ pred) {
    int tidx = threadIdx.x;
    if (tidx >= 16 * 24) return;
    int j = tidx % 24;
    int n = tidx / 24;
    float acc = 0.f;
    for (int f = j; f < j + 3; ++f) {
        int t = 11 + f;
        const float* p = &outbuf[(((size_t)n * TSTEPS + t) * NCOUT + 0) * SS];
        float sloc = 0.f;
        for (int y = 10; y <= 12; ++y)
            for (int x = 19; x <= 29; ++x)
                sloc += p[y * WW + x];
        acc += sloc * (1.f / 33.f);
    }
    pred[n * 24 + j] = acc * (1.f / 3.f);
}

extern "C" void kernel_launch(void* const* d_in, const int* in_sizes, int n_in,
                              void* d_out, int out_size, void* d_ws, size_t ws_size,
                              hipStream_t stream) {
    const float* x      = (const float*)d_in[0];
    const float* conv_w = (const float*)d_in[1];
    const float* conv_b = (const float*)d_in[2];
    const float* h_w    = (const float*)d_in[3];
    const float* h_b    = (const float*)d_in[4];
    const float* m_w    = (const float*)d_in[5];
    const float* m_b    = (const float*)d_in[6];
    const float* z_w    = (const float*)d_in[7];
    const float* z_b    = (const float*)d_in[8];
    const float* o_w    = (const float*)d_in[9];
    const float* o_b    = (const float*)d_in[10];
    const float* out_w  = (const float*)d_in[11];
    const float* out_b  = (const float*)d_in[12];

    float* ws   = (float*)d_ws;
    unsigned* hA    = (unsigned*)(ws + OFF_H);
    float* c    = ws + OFF_C;
    float* m    = ws + OFF_M;
    unsigned* feedp = (unsigned*)(ws + OFF_FEED);
    unsigned* Zp    = (unsigned*)(ws + OFF_Z);
    unsigned* hB    = (unsigned*)(ws + OFF_HB);
    unsigned short* bf2 = (unsigned short*)(ws + OFF_BF2);
    unsigned short* bf  = (unsigned short*)(ws + OFF_BF);
    unsigned short* planes = (unsigned short*)(ws + OFF_QKV);
    const unsigned short* zbuf = (const unsigned short*)(ws + OFF_MKV);
    float* outp = (float*)d_out;

    k_zero<<<4058, 256, 0, stream>>>(ws, 1038688);                 // hA,c,m,feed,Z
    k_zero<<<1352, 256, 0, stream>>>(ws + OFF_HB, 346112);         // hB
    k_zero<<<1, 64, 0, stream>>>(ws + OFF_MKV, 16);                // zero pad for K=32 upper half
    k_prep_bf2<<<1344, 256, 0, stream>>>(conv_w, bf2);
    k_prep_bf<<<1104, 256, 0, stream>>>(o_w, bf);
    k_feed0<<<216, 256, 0, stream>>>(x, feedp);

    for (int t = 0; t < TSTEPS; ++t) {
        k_conv_lstm_mfma<<<dim3(24, 2, 16), 512, 0, stream>>>(feedp, hB, bf2, conv_b, c, hA);
        k_qkv<<<dim3(72, 10), 256, 0, stream>>>(hA, m, h_w, h_b, m_w, m_b, planes);
        k_attn<<<dim3(16, 72), 256, 0, stream>>>(planes, zbuf, z_w, z_b, Zp);
        k_conv_sa<<<dim3(24, 2, 16), 192, 0, stream>>>(Zp, hA, bf, o_b, m, hB);
        k_out_feed<<<288, 256, 0, stream>>>(hB, out_w, out_b, x, outp, feedp, t);
    }
    k_nino<<<1, 384, 0, stream>>>(outp, outp + (size_t)NB * TSTEPS * NCOUT * SS);
}

// Round 11
// 3832.894 us; speedup vs baseline: 1.0410x; 1.0410x over previous
//
#include <hip/hip_runtime.h>
#include <math.h>

#define HD 64
#define DATT 16
#define NCIN 3
#define NCOUT 2
#define HH 24
#define WW 48
#define SS (HH*WW)          // 1152
#define NB 16
#define TSTEPS 37
#define INPUT_FRAMES 12

#define PR 26
#define PC 52
#define PHW (PR*PC)         // 1352

// ---------------- workspace layout (floats) ----------------
#define OFF_H     0                      // hA: post-LSTM h (packed split-bf16 ints, padded)
#define OFF_C     1384448
#define OFF_M     2564096
#define OFF_FEED  3743744                // packed ints
#define OFF_Z     3808640                // packed ints
#define ZERO_END  4154752                // zeroed each launch (1038688 f4)
#define OFF_QKV   4154752                // bf16 attention planes
#define OFF_MKV   5039488                // 64-float zero pad for K=32 upper half
#define OFF_HB    5629312                // hB: carry h (packed ints, padded), zero-init separately
#define OFF_IOG   8873344                // (unused now)
#define OFF_BF2   12412288               // gate-conv B fragments: 344064 ushort
#define OFF_BF    12596864               // out-conv B fragments: 282624 ushort
// end = 12738176 floats = 50.95 MB

typedef __attribute__((ext_vector_type(8))) short short8;
typedef __attribute__((ext_vector_type(4))) float f32x4;

__device__ __forceinline__ float sigmoidf_(float x) {
    return 1.0f / (1.0f + __expf(-x));
}
__device__ __forceinline__ unsigned short f2bf(float f) {
    unsigned u = __float_as_uint(f);
    unsigned r = (u + 0x7fffu + ((u >> 16) & 1u)) >> 16;
    return (unsigned short)r;
}
__device__ __forceinline__ float bf2f(unsigned short b) {
    return __uint_as_float(((unsigned)b) << 16);
}
// packed split-bf16: low16 = hi bf16, high16 = lo bf16 (value ~= hi + lo)
__device__ __forceinline__ unsigned packbf(float f) {
    unsigned short hi = f2bf(f);
    unsigned short lo = f2bf(f - bf2f(hi));
    return ((unsigned)lo << 16) | (unsigned)hi;
}
__device__ __forceinline__ float unpackbf(unsigned pk) {
    return __uint_as_float(pk << 16) + __uint_as_float(pk & 0xffff0000u);
}
__device__ __forceinline__ unsigned cvt_pk_bf16(float a, float b) {
    unsigned r;
    asm("v_cvt_pk_bf16_f32 %0, %1, %2" : "=v"(r) : "v"(a), "v"(b));
    return r;
}
// Row permutation for attention K planes (PV A-fragment order)
__device__ __forceinline__ int permrow(int t) {
    int kb = t >> 5, tl = t & 31;
    int quad = tl >> 3, rr = tl & 7;
    return kb * 32 + ((rr >= 4) ? 16 : 0) + quad * 4 + (rr & 3);
}

// build hi/lo bf16 A-fragments from 8 packed ints (2x int4)
#define MKFRAG(P0, P1, ah, al) do {                                  \
    ah.i[0] = (P0.y << 16) | (P0.x & 0xffff);                        \
    ah.i[1] = (P0.w << 16) | (P0.z & 0xffff);                        \
    ah.i[2] = (P1.y << 16) | (P1.x & 0xffff);                        \
    ah.i[3] = (P1.w << 16) | (P1.z & 0xffff);                        \
    al.i[0] = (P0.y & 0xffff0000) | ((unsigned)P0.x >> 16);          \
    al.i[1] = (P0.w & 0xffff0000) | ((unsigned)P0.z >> 16);          \
    al.i[2] = (P1.y & 0xffff0000) | ((unsigned)P1.x >> 16);          \
    al.i[3] = (P1.w & 0xffff0000) | ((unsigned)P1.z >> 16);          \
} while (0)

__global__ void k_zero(float* __restrict__ p, int n4) {
    int i = blockIdx.x * blockDim.x + threadIdx.x;
    if (i < n4) ((float4*)p)[i] = make_float4(0.f, 0.f, 0.f, 0.f);
}

// ---- B fragment prep for MFMA gate conv ----
__global__ void k_prep_bf2(const float* __restrict__ cw, unsigned short* __restrict__ bbuf) {
    int idx = blockIdx.x * 256 + threadIdx.x;
    if (idx >= 344064) return;
    int j    = idx & 7;
    int lane = (idx >> 3) & 63;
    int ki   = (idx >> 9) % 21;
    int nt   = (idx / 10752) % 16;
    int p    = idx / 172032;
    int k = ki * 32 + (lane >> 4) * 8 + j;
    int ncol = nt * 16 + (lane & 15);
    unsigned short v = 0;
    if (k < 648) {
        int c = k % 72, kt = k / 72;
        if (c < 67) {
            float w = cw[ncol * 603 + c * 9 + kt];
            unsigned short hi = f2bf(w);
            v = (p == 0) ? hi : f2bf(w - bf2f(hi));
        }
    }
    bbuf[idx] = v;
}

// ---- B fragment prep for MFMA out conv ----
__global__ void k_prep_bf(const float* __restrict__ ow, unsigned short* __restrict__ bbuf) {
    int idx = blockIdx.x * 256 + threadIdx.x;
    if (idx >= 282624) return;
    int j    = idx & 7;
    int lane = (idx >> 3) & 63;
    int ki   = (idx >> 9) % 23;
    int nt   = (idx / 11776) % 12;
    int p    = idx / 141312;
    int k = ki * 32 + (lane >> 4) * 8 + j;
    int ncol = nt * 16 + (lane & 15);
    unsigned short v = 0;
    if (k < 720) {
        int c = k % 80, kt = k / 80;
        float w = ow[ncol * 720 + c * 9 + kt];
        unsigned short hi = f2bf(w);
        v = (p == 0) ? hi : f2bf(w - bf2f(hi));
    }
    bbuf[idx] = v;
}

// ---------------- initial feed (t=0), packed ----------------
__global__ void k_feed0(const float* __restrict__ x, unsigned* __restrict__ feed) {
    int i = blockIdx.x * blockDim.x + threadIdx.x;
    if (i >= NB * 3 * SS) return;
    int s = i % SS;
    int ch = (i / SS) % 3;
    int n = i / (3 * SS);
    int y = s / WW, xx = s % WW;
    float v = x[(((size_t)(n * TSTEPS + 0) * HH + y) * WW + xx) * NCIN + ch];
    feed[((size_t)(n * 3 + ch) * PR + (y + 1)) * PC + (xx + 1)] = packbf(v);
}

// ---------------- MFMA gate conv + FUSED LSTM gates (R8 champion) ----------
// grid (24 y, 2 nb, 16 n); block 256 = 4 waves, wave = GATE. A-tile stride 76.
// c/bias loads issued at kernel entry -> latency hidden under staging+K-loop.
#define ASTR2 76
#define ZOFF2 (3*52*ASTR2)
__global__ __launch_bounds__(256) void k_conv_lstm_mfma(
    const unsigned* __restrict__ feed, const unsigned* __restrict__ hin,
    const unsigned short* __restrict__ bbuf, const float* __restrict__ cb,
    float* __restrict__ c, unsigned* __restrict__ hout)
{
    __shared__ __align__(16) int lds[3 * 52 * ASTR2 + 8];
    const int y0 = blockIdx.x;
    const int nb = blockIdx.y;
    const int n  = blockIdx.z;
    const int tid = threadIdx.x;

    // ---- epilogue prefetch (addresses known at entry) ----
    const int ech = tid & 31;
    const int exg = tid >> 5;                    // 0..7
    const int egch = nb * 32 + ech;
    const size_t ecbase = ((size_t)(n * HD + egch) * HH + y0) * WW + exg * 6;
    float cpre[6];
#pragma unroll
    for (int k = 0; k < 6; ++k) cpre[k] = c[ecbase + k];
    const float ebi = cb[egch], ebf = cb[64 + egch];
    const float ebo = cb[128 + egch], ebg = cb[192 + egch];

    const unsigned* fbase = feed + (size_t)n * 3 * PHW;
    const unsigned* hbase = hin + (size_t)n * HD * PHW;
    for (int e = tid; e < 2808; e += 256) {
        int grp = e / 156;
        int r2  = e - grp * 156;
        int pr = r2 / 52, pc = r2 - pr * 52;
        int cc0 = grp * 4;
        int vv[4];
#pragma unroll
        for (int j = 0; j < 4; ++j) {
            int cc = cc0 + j;
            int t = 0;
            if (cc < 3)        t = (int)fbase[(size_t)cc * PHW + (y0 + pr) * PC + pc];
            else if (cc < 67)  t = (int)hbase[(size_t)(cc - 3) * PHW + (y0 + pr) * PC + pc];
            vv[j] = t;
        }
        int4 v; v.x = vv[0]; v.y = vv[1]; v.z = vv[2]; v.w = vv[3];
        *(int4*)&lds[r2 * ASTR2 + cc0] = v;
    }
    if (tid < 8) lds[ZOFF2 + tid] = 0;
    __syncthreads();

    const int wv = tid >> 6;          // wave = gate 0..3
    const int lane = tid & 63;
    const int mcol = lane & 15;
    const int quad = lane >> 4;

    f32x4 acc[2][3];
#pragma unroll
    for (int jg = 0; jg < 2; ++jg)
#pragma unroll
        for (int xt = 0; xt < 3; ++xt) acc[jg][xt] = (f32x4){0.f, 0.f, 0.f, 0.f};

    const unsigned short* b0 = bbuf + ((size_t)(wv * 4 + nb * 2 + 0) * 21) * 512 + lane * 8;
    const unsigned short* b1 = bbuf + ((size_t)(wv * 4 + nb * 2 + 1) * 21) * 512 + lane * 8;

    short8 cb0h = *(const short8*)(b0);
    short8 cb0l = *(const short8*)(b0 + 172032);
    short8 cb1h = *(const short8*)(b1);
    short8 cb1l = *(const short8*)(b1 + 172032);

    for (int ki = 0; ki < 21; ++ki) {
        int kn = (ki < 20) ? (ki + 1) * 512 : 20 * 512;
        short8 nb0h = *(const short8*)(b0 + kn);
        short8 nb0l = *(const short8*)(b0 + kn + 172032);
        short8 nb1h = *(const short8*)(b1 + kn);
        short8 nb1l = *(const short8*)(b1 + kn + 172032);

        int k0 = ki * 32 + quad * 8;
        int ab, step;
        if (k0 < 648) {
            int kt = k0 / 72;
            int c0 = k0 - kt * 72;
            int dy = kt / 3, dx = kt - dy * 3;
            ab = (dy * 52 + mcol + dx) * ASTR2 + c0;
            step = 16 * ASTR2;
        } else {
            ab = ZOFF2; step = 0;
        }
        int4 A0 = *(const int4*)&lds[ab],            A1 = *(const int4*)&lds[ab + 4];
        int4 B0 = *(const int4*)&lds[ab + step],     B1 = *(const int4*)&lds[ab + step + 4];
        int4 C0 = *(const int4*)&lds[ab + 2 * step], C1 = *(const int4*)&lds[ab + 2 * step + 4];

        union { int i[4]; short8 v; } ah, al;
        MKFRAG(A0, A1, ah, al);
        acc[0][0] = __builtin_amdgcn_mfma_f32_16x16x32_bf16(ah.v, cb0h, acc[0][0], 0, 0, 0);
        acc[0][0] = __builtin_amdgcn_mfma_f32_16x16x32_bf16(ah.v, cb0l, acc[0][0], 0, 0, 0);
        acc[0][0] = __builtin_amdgcn_mfma_f32_16x16x32_bf16(al.v, cb0h, acc[0][0], 0, 0, 0);
        acc[1][0] = __builtin_amdgcn_mfma_f32_16x16x32_bf16(ah.v, cb1h, acc[1][0], 0, 0, 0);
        acc[1][0] = __builtin_amdgcn_mfma_f32_16x16x32_bf16(ah.v, cb1l, acc[1][0], 0, 0, 0);
        acc[1][0] = __builtin_amdgcn_mfma_f32_16x16x32_bf16(al.v, cb1h, acc[1][0], 0, 0, 0);
        MKFRAG(B0, B1, ah, al);
        acc[0][1] = __builtin_amdgcn_mfma_f32_16x16x32_bf16(ah.v, cb0h, acc[0][1], 0, 0, 0);
        acc[0][1] = __builtin_amdgcn_mfma_f32_16x16x32_bf16(ah.v, cb0l, acc[0][1], 0, 0, 0);
        acc[0][1] = __builtin_amdgcn_mfma_f32_16x16x32_bf16(al.v, cb0h, acc[0][1], 0, 0, 0);
        acc[1][1] = __builtin_amdgcn_mfma_f32_16x16x32_bf16(ah.v, cb1h, acc[1][1], 0, 0, 0);
        acc[1][1] = __builtin_amdgcn_mfma_f32_16x16x32_bf16(ah.v, cb1l, acc[1][1], 0, 0, 0);
        acc[1][1] = __builtin_amdgcn_mfma_f32_16x16x32_bf16(al.v, cb1h, acc[1][1], 0, 0, 0);
        MKFRAG(C0, C1, ah, al);
        acc[0][2] = __builtin_amdgcn_mfma_f32_16x16x32_bf16(ah.v, cb0h, acc[0][2], 0, 0, 0);
        acc[0][2] = __builtin_amdgcn_mfma_f32_16x16x32_bf16(ah.v, cb0l, acc[0][2], 0, 0, 0);
        acc[0][2] = __builtin_amdgcn_mfma_f32_16x16x32_bf16(al.v, cb0h, acc[0][2], 0, 0, 0);
        acc[1][2] = __builtin_amdgcn_mfma_f32_16x16x32_bf16(ah.v, cb1h, acc[1][2], 0, 0, 0);
        acc[1][2] = __builtin_amdgcn_mfma_f32_16x16x32_bf16(ah.v, cb1l, acc[1][2], 0, 0, 0);
        acc[1][2] = __builtin_amdgcn_mfma_f32_16x16x32_bf16(al.v, cb1h, acc[1][2], 0, 0, 0);

        cb0h = nb0h; cb0l = nb0l; cb1h = nb1h; cb1l = nb1l;
    }

    // ---- cross-wave gate exchange through the dead A-tile LDS ----
    __syncthreads();
    float* exch = (float*)lds;        // [frag=(gate*2+jg)*3+xt][row16 x str17][col]
#pragma unroll
    for (int jg = 0; jg < 2; ++jg)
#pragma unroll
        for (int xt = 0; xt < 3; ++xt)
#pragma unroll
            for (int r = 0; r < 4; ++r)
                exch[((wv * 2 + jg) * 3 + xt) * 272 + (quad * 4 + r) * 17 + mcol] = acc[jg][xt][r];
    __syncthreads();

    // epilogue: 32 channels x 48 x; thread = (ch32 = tid&31, xg = tid>>5)
    const int jg = ech >> 4, col = ech & 15;
    unsigned* hp = hout + ((size_t)(n * HD + egch) * PR + y0 + 1) * PC + 1;
#pragma unroll
    for (int k = 0; k < 6; ++k) {
        int x = exg * 6 + k;
        int xt = x >> 4, row = x & 15;
        float iv = sigmoidf_(exch[((0 * 2 + jg) * 3 + xt) * 272 + row * 17 + col] + ebi);
        float fv = sigmoidf_(exch[((1 * 2 + jg) * 3 + xt) * 272 + row * 17 + col] + ebf);
        float ov = sigmoidf_(exch[((2 * 2 + jg) * 3 + xt) * 272 + row * 17 + col] + ebo);
        float gv = tanhf    (exch[((3 * 2 + jg) * 3 + xt) * 272 + row * 17 + col] + ebg);
        float cn = fv * cpre[k] + iv * gv;
        float hn = ov * tanhf(cn);
        c[ecbase + k] = cn;
        hp[x] = packbf(hn);
    }
}

// ---------------- MFMA out conv + FUSED SA gates (R8 champion) ----------------
// grid (24 y, 2 cb, 16 n); block 192 = 3 waves, wave = GATE (si/sg/so).
#define ASTR (84)
#define ZOFF (3*52*ASTR)
__global__ __launch_bounds__(192) void k_conv_sa(
    const unsigned* __restrict__ Zin, const unsigned* __restrict__ hin,
    const unsigned short* __restrict__ bbuf, const float* __restrict__ ob,
    float* __restrict__ m, unsigned* __restrict__ hout)
{
    __shared__ __align__(16) int lds[3 * 52 * ASTR + 8];
    const int y0 = blockIdx.x;
    const int cbk = blockIdx.y;
    const int n  = blockIdx.z;
    const int tid = threadIdx.x;

    // ---- epilogue prefetch ----
    const int ech = tid & 31;
    const int exg = tid >> 5;                    // 0..5
    const int egch = cbk * 32 + ech;
    float* emrow = m + ((size_t)(n * HD + egch) * HH + y0) * WW;
    float mpre[8];
    {
        float4 a = *(const float4*)&emrow[exg * 8];
        float4 b = *(const float4*)&emrow[exg * 8 + 4];
        mpre[0] = a.x; mpre[1] = a.y; mpre[2] = a.z; mpre[3] = a.w;
        mpre[4] = b.x; mpre[5] = b.y; mpre[6] = b.z; mpre[7] = b.w;
    }
    const float ebsi = ob[egch], ebsg = ob[64 + egch], ebso = ob[128 + egch];

    const unsigned* zbase = Zin + (size_t)n * DATT * PHW;
    const unsigned* hbase = hin + (size_t)n * HD * PHW;
    for (int e = tid; e < 3120; e += 192) {   // 20 quads x 156 spatial
        int grp = e / 156;
        int r2  = e - grp * 156;
        int pr = r2 / 52, pc = r2 - pr * 52;
        int cc0 = grp * 4;
        int vv[4];
#pragma unroll
        for (int j = 0; j < 4; ++j) {
            int cc = cc0 + j;
            const unsigned* src = (cc < 16) ? (zbase + (size_t)cc * PHW)
                                            : (hbase + (size_t)(cc - 16) * PHW);
            vv[j] = (int)src[(y0 + pr) * PC + pc];
        }
        int4 v; v.x = vv[0]; v.y = vv[1]; v.z = vv[2]; v.w = vv[3];
        *(int4*)&lds[r2 * ASTR + cc0] = v;
    }
    if (tid < 8) lds[ZOFF + tid] = 0;
    __syncthreads();

    const int wv = tid >> 6;          // wave = gate 0..2 (si/sg/so)
    const int lane = tid & 63;
    const int mcol = lane & 15;
    const int quad = lane >> 4;

    f32x4 acc[2][3];
#pragma unroll
    for (int j = 0; j < 2; ++j)
#pragma unroll
        for (int xt = 0; xt < 3; ++xt) acc[j][xt] = (f32x4){0.f, 0.f, 0.f, 0.f};

    const unsigned short* b0 = bbuf + ((size_t)(wv * 4 + cbk * 2 + 0) * 23) * 512 + lane * 8;
    const unsigned short* b1 = bbuf + ((size_t)(wv * 4 + cbk * 2 + 1) * 23) * 512 + lane * 8;

    short8 cb0h = *(const short8*)(b0);
    short8 cb0l = *(const short8*)(b0 + 141312);
    short8 cb1h = *(const short8*)(b1);
    short8 cb1l = *(const short8*)(b1 + 141312);

    for (int ki = 0; ki < 23; ++ki) {
        int kn = (ki < 22) ? (ki + 1) * 512 : 22 * 512;
        short8 nb0h = *(const short8*)(b0 + kn);
        short8 nb0l = *(const short8*)(b0 + kn + 141312);
        short8 nb1h = *(const short8*)(b1 + kn);
        short8 nb1l = *(const short8*)(b1 + kn + 141312);

        int k0 = ki * 32 + quad * 8;
        int ab, step;
        if (k0 < 720) {
            int kt = k0 / 80;
            int c0 = k0 - kt * 80;
            int dy = kt / 3, dx = kt - dy * 3;
            ab = (dy * 52 + mcol + dx) * ASTR + c0;
            step = 16 * ASTR;
        } else {
            ab = ZOFF; step = 0;
        }
        int4 A0 = *(const int4*)&lds[ab],            A1 = *(const int4*)&lds[ab + 4];
        int4 B0 = *(const int4*)&lds[ab + step],     B1 = *(const int4*)&lds[ab + step + 4];
        int4 C0 = *(const int4*)&lds[ab + 2 * step], C1 = *(const int4*)&lds[ab + 2 * step + 4];

        union { int i[4]; short8 v; } ah, al;
        MKFRAG(A0, A1, ah, al);
        acc[0][0] = __builtin_amdgcn_mfma_f32_16x16x32_bf16(ah.v, cb0h, acc[0][0], 0, 0, 0);
        acc[0][0] = __builtin_amdgcn_mfma_f32_16x16x32_bf16(ah.v, cb0l, acc[0][0], 0, 0, 0);
        acc[0][0] = __builtin_amdgcn_mfma_f32_16x16x32_bf16(al.v, cb0h, acc[0][0], 0, 0, 0);
        acc[1][0] = __builtin_amdgcn_mfma_f32_16x16x32_bf16(ah.v, cb1h, acc[1][0], 0, 0, 0);
        acc[1][0] = __builtin_amdgcn_mfma_f32_16x16x32_bf16(ah.v, cb1l, acc[1][0], 0, 0, 0);
        acc[1][0] = __builtin_amdgcn_mfma_f32_16x16x32_bf16(al.v, cb1h, acc[1][0], 0, 0, 0);
        MKFRAG(B0, B1, ah, al);
        acc[0][1] = __builtin_amdgcn_mfma_f32_16x16x32_bf16(ah.v, cb0h, acc[0][1], 0, 0, 0);
        acc[0][1] = __builtin_amdgcn_mfma_f32_16x16x32_bf16(ah.v, cb0l, acc[0][1], 0, 0, 0);
        acc[0][1] = __builtin_amdgcn_mfma_f32_16x16x32_bf16(al.v, cb0h, acc[0][1], 0, 0, 0);
        acc[1][1] = __builtin_amdgcn_mfma_f32_16x16x32_bf16(ah.v, cb1h, acc[1][1], 0, 0, 0);
        acc[1][1] = __builtin_amdgcn_mfma_f32_16x16x32_bf16(ah.v, cb1l, acc[1][1], 0, 0, 0);
        acc[1][1] = __builtin_amdgcn_mfma_f32_16x16x32_bf16(al.v, cb1h, acc[1][1], 0, 0, 0);
        MKFRAG(C0, C1, ah, al);
        acc[0][2] = __builtin_amdgcn_mfma_f32_16x16x32_bf16(ah.v, cb0h, acc[0][2], 0, 0, 0);
        acc[0][2] = __builtin_amdgcn_mfma_f32_16x16x32_bf16(ah.v, cb0l, acc[0][2], 0, 0, 0);
        acc[0][2] = __builtin_amdgcn_mfma_f32_16x16x32_bf16(al.v, cb0h, acc[0][2], 0, 0, 0);
        acc[1][2] = __builtin_amdgcn_mfma_f32_16x16x32_bf16(ah.v, cb1h, acc[1][2], 0, 0, 0);
        acc[1][2] = __builtin_amdgcn_mfma_f32_16x16x32_bf16(ah.v, cb1l, acc[1][2], 0, 0, 0);
        acc[1][2] = __builtin_amdgcn_mfma_f32_16x16x32_bf16(al.v, cb1h, acc[1][2], 0, 0, 0);

        cb0h = nb0h; cb0l = nb0l; cb1h = nb1h; cb1l = nb1l;
    }

    // ---- cross-wave gate exchange ----
    __syncthreads();
    float* exch = (float*)lds;        // [frag=(gate*2+j)*3+xt][row16 x str17][col]
#pragma unroll
    for (int j = 0; j < 2; ++j)
#pragma unroll
        for (int xt = 0; xt < 3; ++xt)
#pragma unroll
            for (int r = 0; r < 4; ++r)
                exch[((wv * 2 + j) * 3 + xt) * 272 + (quad * 4 + r) * 17 + mcol] = acc[j][xt][r];
    __syncthreads();

    // fused SA-gate epilogue: thread = (ech, exg in 0..5), 8 x each
    const int jg = ech >> 4, col = ech & 15;
    unsigned* hp = hout + ((size_t)(n * HD + egch) * PR + y0 + 1) * PC + 1;
#pragma unroll
    for (int k = 0; k < 8; ++k) {
        int x = exg * 8 + k;
        int xt = x >> 4, row = x & 15;
        float si = sigmoidf_(exch[((0 * 2 + jg) * 3 + xt) * 272 + row * 17 + col] + ebsi);
        float sg = tanhf    (exch[((1 * 2 + jg) * 3 + xt) * 272 + row * 17 + col] + ebsg);
        float so =           exch[((2 * 2 + jg) * 3 + xt) * 272 + row * 17 + col] + ebso;
        float mn = si * sg + (1.f - si) * mpre[k];
        emrow[x] = mn;
        hp[x] = packbf(sigmoidf_(so) * mn);
    }
}

// ---------------- 1x1 q/k/v + mk/mv projections -> bf16 MFMA planes ----------------
__global__ __launch_bounds__(256) void k_qkv(
    const unsigned* __restrict__ h, const float* __restrict__ m,
    const float* __restrict__ hw, const float* __restrict__ hb,
    const float* __restrict__ mw, const float* __restrict__ mb,
    unsigned short* __restrict__ pl) {
    __shared__ float lw[512];
    __shared__ float lb[8];
    const int g = blockIdx.y;
    const int tid = threadIdx.x;
    const float* wsrc = (g < 6) ? (hw + g * 512) : (mw + (g - 6) * 512);
    const float* bsrc = (g < 6) ? (hb + g * 8) : (mb + (g - 6) * 8);
    for (int i = tid; i < 512; i += 256) lw[i] = wsrc[i];
    if (tid < 8) lb[tid] = bsrc[tid];
    __syncthreads();

    int idx = blockIdx.x * 256 + tid;
    int s = idx % SS;
    int n = idx / SS;

    float reg[HD];
    if (g < 6) {
        int y = s / WW, x = s % WW;
        const unsigned* src = h + (size_t)n * HD * PHW + (y + 1) * PC + (x + 1);
#pragma unroll
        for (int ic = 0; ic < HD; ++ic) reg[ic] = unpackbf(src[ic * PHW]);
    } else {
        const float* src = m + (size_t)n * HD * SS + s;
#pragma unroll
        for (int ic = 0; ic < HD; ++ic) reg[ic] = src[ic * SS];
    }

    float out[8];
#pragma unroll
    for (int j = 0; j < 8; ++j) {
        const float* wr = &lw[j * HD];
        float a = lb[j];
#pragma unroll
        for (int ic = 0; ic < HD; ++ic) a += reg[ic] * wr[ic];
        out[j] = a;
    }

    unsigned short* bq  = pl;
    unsigned short* akh = pl + 294912;
    unsigned short* akm = pl + 589824;
    unsigned short* bvh = pl + 884736;
    unsigned short* bvm = pl + 1179648;
    const int c0 = (g & 1) * 8;

    if (g < 2) {                       // Q: [n][s][16]
        unsigned w0 = (unsigned)f2bf(out[0]) | ((unsigned)f2bf(out[1]) << 16);
        unsigned w1 = (unsigned)f2bf(out[2]) | ((unsigned)f2bf(out[3]) << 16);
        unsigned w2 = (unsigned)f2bf(out[4]) | ((unsigned)f2bf(out[5]) << 16);
        unsigned w3 = (unsigned)f2bf(out[6]) | ((unsigned)f2bf(out[7]) << 16);
        *(uint4*)&bq[((size_t)n * SS + s) * 16 + c0] = make_uint4(w0, w1, w2, w3);
    } else if (g < 4 || (g >= 6 && g < 8)) {   // K planes, permuted rows
        int row = permrow(s);
        unsigned short* base = (g < 4) ? akh : akm;
        unsigned w0 = (unsigned)f2bf(out[0]) | ((unsigned)f2bf(out[1]) << 16);
        unsigned w1 = (unsigned)f2bf(out[2]) | ((unsigned)f2bf(out[3]) << 16);
        unsigned w2 = (unsigned)f2bf(out[4]) | ((unsigned)f2bf(out[5]) << 16);
        unsigned w3 = (unsigned)f2bf(out[6]) | ((unsigned)f2bf(out[7]) << 16);
        *(uint4*)&base[((size_t)n * SS + row) * 16 + c0] = make_uint4(w0, w1, w2, w3);
    } else {                            // V planes, transposed [n][d][1152]
        unsigned short* base = (g < 6) ? bvh : bvm;
#pragma unroll
        for (int j = 0; j < 8; ++j)
            base[((size_t)n * 16 + c0 + j) * SS + s] = f2bf(out[j]);
    }
}

// ---------------- MFMA dual spatial attention + z 1x1 ----------------
__global__ __launch_bounds__(256) void k_attn(
    const unsigned short* __restrict__ pl, const unsigned short* __restrict__ zbuf,
    const float* __restrict__ zw, const float* __restrict__ zb,
    unsigned* __restrict__ Z)
{
    __shared__ float ldsO[4][2][16][16];
    __shared__ float ldsF[2][16][16];
    __shared__ float ldsL[4][2][16];
    __shared__ float ldsLF[2][16];

    const int n   = blockIdx.x;
    const int qt  = blockIdx.y;
    const int tid = threadIdx.x;
    const int wv  = tid >> 6;
    const int lane = tid & 63;
    const int col  = lane & 15;
    const int quad = lane >> 4;
    const bool hi  = quad >= 2;          // K=32 upper half -> zeros

    const unsigned short* bq  = pl;
    const unsigned short* akh = pl + 294912;
    const unsigned short* akm = pl + 589824;
    const unsigned short* bvh = pl + 884736;
    const unsigned short* bvm = pl + 1179648;

    const size_t nb = (size_t)n * 18432;
    const int stepk = hi ? 0 : 512;
    const int subk  = hi ? 0 : 256;
    const unsigned short* qp  = hi ? zbuf : (bq  + nb + ((size_t)(qt * 16 + col)) * 16 + quad * 8);
    const unsigned short* khb = hi ? zbuf : (akh + nb + col * 16 + quad * 8);
    const unsigned short* kmb = hi ? zbuf : (akm + nb + col * 16 + quad * 8);
    const unsigned short* vhb = bvh + nb + (size_t)col * SS + quad * 8;
    const unsigned short* vmb = bvm + nb + (size_t)col * SS + quad * 8;

    short8 qf = *(const short8*)qp;

    f32x4 oh = (f32x4){0.f,0.f,0.f,0.f}, om = (f32x4){0.f,0.f,0.f,0.f};
    float lh = 0.f, lm = 0.f;
    const int kb0 = wv * 9, kb1 = kb0 + 9;
    for (int kb = kb0; kb < kb1; ++kb) {
        const unsigned short* kh0 = khb + (size_t)kb * stepk;
        const unsigned short* km0 = kmb + (size_t)kb * stepk;
        short8 khA = *(const short8*)kh0;
        short8 khB = *(const short8*)(kh0 + subk);
        short8 kmA = *(const short8*)km0;
        short8 kmB = *(const short8*)(km0 + subk);
        short8 vh  = *(const short8*)(vhb + (size_t)kb * 32);
        short8 vm  = *(const short8*)(vmb + (size_t)kb * 32);
        const f32x4 z4 = (f32x4){0.f,0.f,0.f,0.f};
        f32x4 sA = __builtin_amdgcn_mfma_f32_16x16x32_bf16(khA, qf, z4, 0, 0, 0);
        f32x4 sB = __builtin_amdgcn_mfma_f32_16x16x32_bf16(khB, qf, z4, 0, 0, 0);
        f32x4 tA = __builtin_amdgcn_mfma_f32_16x16x32_bf16(kmA, qf, z4, 0, 0, 0);
        f32x4 tB = __builtin_amdgcn_mfma_f32_16x16x32_bf16(kmB, qf, z4, 0, 0, 0);

        float pa0 = __expf(0.25f * sA[0]), pa1 = __expf(0.25f * sA[1]);
        float pa2 = __expf(0.25f * sA[2]), pa3 = __expf(0.25f * sA[3]);
        float pb0 = __expf(0.25f * sB[0]), pb1 = __expf(0.25f * sB[1]);
        float pb2 = __expf(0.25f * sB[2]), pb3 = __expf(0.25f * sB[3]);
        lh += (pa0 + pa1 + pa2 + pa3) + (pb0 + pb1 + pb2 + pb3);
        union { unsigned u[4]; short8 v; } ph;
        ph.u[0] = cvt_pk_bf16(pa0, pa1); ph.u[1] = cvt_pk_bf16(pa2, pa3);
        ph.u[2] = cvt_pk_bf16(pb0, pb1); ph.u[3] = cvt_pk_bf16(pb2, pb3);
        oh = __builtin_amdgcn_mfma_f32_16x16x32_bf16(ph.v, vh, oh, 0, 0, 0);

        float qa0 = __expf(0.25f * tA[0]), qa1 = __expf(0.25f * tA[1]);
        float qa2 = __expf(0.25f * tA[2]), qa3 = __expf(0.25f * tA[3]);
        float qb0 = __expf(0.25f * tB[0]), qb1 = __expf(0.25f * tB[1]);
        float qb2 = __expf(0.25f * tB[2]), qb3 = __expf(0.25f * tB[3]);
        lm += (qa0 + qa1 + qa2 + qa3) + (qb0 + qb1 + qb2 + qb3);
        union { unsigned u[4]; short8 v; } pm;
        pm.u[0] = cvt_pk_bf16(qa0, qa1); pm.u[1] = cvt_pk_bf16(qa2, qa3);
        pm.u[2] = cvt_pk_bf16(qb0, qb1); pm.u[3] = cvt_pk_bf16(qb2, qb3);
        om = __builtin_amdgcn_mfma_f32_16x16x32_bf16(pm.v, vm, om, 0, 0, 0);
    }

    lh += __shfl_xor(lh, 16); lh += __shfl_xor(lh, 32);
    lm += __shfl_xor(lm, 16); lm += __shfl_xor(lm, 32);

#pragma unroll
    for (int r = 0; r < 4; ++r) {
        ldsO[wv][0][quad * 4 + r][col] = oh[r];
        ldsO[wv][1][quad * 4 + r][col] = om[r];
    }
    if (lane < 16) { ldsL[wv][0][lane] = lh; ldsL[wv][1][lane] = lm; }
    __syncthreads();

    if (tid < 128) {
        int a_ = tid >> 6, rem = tid & 63, q_ = rem >> 2, j4 = (rem & 3) * 4;
        float4 s4 = make_float4(0.f, 0.f, 0.f, 0.f);
#pragma unroll
        for (int w = 0; w < 4; ++w) {
            float4 v = *(const float4*)&ldsO[w][a_][q_][j4];
            s4.x += v.x; s4.y += v.y; s4.z += v.z; s4.w += v.w;
        }
        *(float4*)&ldsF[a_][q_][j4] = s4;
    } else if (tid < 160) {
        int e = tid - 128, a_ = e >> 4, q_ = e & 15;
        ldsLF[a_][q_] = ldsL[0][a_][q_] + ldsL[1][a_][q_] +
                        ldsL[2][a_][q_] + ldsL[3][a_][q_];
    }
    __syncthreads();

    const int q  = tid & 15;
    const int zc = tid >> 4;
    float iLh = 1.f / ldsLF[0][q], iLm = 1.f / ldsLF[1][q];
    const float* zr = zw + zc * 32;
    float a = zb[zc];
#pragma unroll
    for (int j = 0; j < 16; ++j)
        a += zr[j] * (ldsF[0][q][j] * iLh) + zr[16 + j] * (ldsF[1][q][j] * iLm);
    int s = qt * 16 + q;
    int y = s / WW, x = s % WW;
    Z[((size_t)(n * DATT + zc) * PR + y + 1) * PC + x + 1] = packbf(a);
}

// ---------------- out 1x1 (64->2) + next-step feed (packed), fused ----------------
// 288 blocks; each spatial point handled by 4 lanes (16 ic each) + shfl reduce.
__global__ __launch_bounds__(256) void k_out_feed(
    const unsigned* __restrict__ h, const float* __restrict__ ow,
    const float* __restrict__ ob, const float* __restrict__ x,
    float* __restrict__ outbuf, unsigned* __restrict__ feed, int t) {
    const int tid = threadIdx.x;
    const int lane = tid & 63;
    const int wv = tid >> 6;
    const int part = lane >> 4;     // 0..3 -> ic group
    const int sl = lane & 15;
    int sidx = blockIdx.x * 64 + wv * 16 + sl;   // 0..18431
    int s = sidx % SS;
    int n = sidx / SS;
    int y = s / WW, xx = s % WW;
    const unsigned* src = h + (size_t)n * HD * PHW + (y + 1) * PC + (xx + 1);
    float o0 = 0.f, o1 = 0.f;
#pragma unroll
    for (int i = 0; i < 16; ++i) {
        int ic = part * 16 + i;
        float r = unpackbf(src[ic * PHW]);
        o0 += r * ow[ic];
        o1 += r * ow[HD + ic];
    }
    o0 += __shfl_xor(o0, 16); o0 += __shfl_xor(o0, 32);
    o1 += __shfl_xor(o1, 16); o1 += __shfl_xor(o1, 32);

    if (part == 0) {
        o0 += ob[0]; o1 += ob[1];
        outbuf[(((size_t)n * TSTEPS + t) * NCOUT + 0) * SS + s] = o0;
        outbuf[(((size_t)n * TSTEPS + t) * NCOUT + 1) * SS + s] = o1;
        if (t + 1 < TSTEPS) {
            int t1 = t + 1;
            const float* xp = &x[(((size_t)(n * TSTEPS + t1) * HH + y) * WW + xx) * NCIN];
            float f0, f1, f2 = xp[2];
            if (t1 < INPUT_FRAMES) { f0 = xp[0]; f1 = xp[1]; }
            else { f0 = o0; f1 = o1; }
            size_t fb = ((size_t)(n * 3 + 0) * PR + y + 1) * PC + xx + 1;
            feed[fb] = packbf(f0);
            feed[fb + PHW] = packbf(f1);
            feed[fb + 2 * (size_t)PHW] = packbf(f2);
        }
    }
}

// ---------------- nino prediction ----------------
__global__ void k_nino(const float* __restrict__ outbuf, float* __restrict__ pred) {
    int tidx = threadIdx.x;
    if (tidx >= 16 * 24) return;
    int j = tidx % 24;
    int n = tidx / 24;
    float acc = 0.f;
    for (int f = j; f < j + 3; ++f) {
        int t = 11 + f;
        const float* p = &outbuf[(((size_t)n * TSTEPS + t) * NCOUT + 0) * SS];
        float sloc = 0.f;
        for (int y = 10; y <= 12; ++y)
            for (int x = 19; x <= 29; ++x)
                sloc += p[y * WW + x];
        acc += sloc * (1.f / 33.f);
    }
    pred[n * 24 + j] = acc * (1.f / 3.f);
}

extern "C" void kernel_launch(void* const* d_in, const int* in_sizes, int n_in,
                              void* d_out, int out_size, void* d_ws, size_t ws_size,
                              hipStream_t stream) {
    const float* x      = (const float*)d_in[0];
    const float* conv_w = (const float*)d_in[1];
    const float* conv_b = (const float*)d_in[2];
    const float* h_w    = (const float*)d_in[3];
    const float* h_b    = (const float*)d_in[4];
    const float* m_w    = (const float*)d_in[5];
    const float* m_b    = (const float*)d_in[6];
    const float* z_w    = (const float*)d_in[7];
    const float* z_b    = (const float*)d_in[8];
    const float* o_w    = (const float*)d_in[9];
    const float* o_b    = (const float*)d_in[10];
    const float* out_w  = (const float*)d_in[11];
    const float* out_b  = (const float*)d_in[12];

    float* ws   = (float*)d_ws;
    unsigned* hA    = (unsigned*)(ws + OFF_H);
    float* c    = ws + OFF_C;
    float* m    = ws + OFF_M;
    unsigned* feedp = (unsigned*)(ws + OFF_FEED);
    unsigned* Zp    = (unsigned*)(ws + OFF_Z);
    unsigned* hB    = (unsigned*)(ws + OFF_HB);
    unsigned short* bf2 = (unsigned short*)(ws + OFF_BF2);
    unsigned short* bf  = (unsigned short*)(ws + OFF_BF);
    unsigned short* planes = (unsigned short*)(ws + OFF_QKV);
    const unsigned short* zbuf = (const unsigned short*)(ws + OFF_MKV);
    float* outp = (float*)d_out;

    k_zero<<<4058, 256, 0, stream>>>(ws, 1038688);                 // hA,c,m,feed,Z
    k_zero<<<1352, 256, 0, stream>>>(ws + OFF_HB, 346112);         // hB
    k_zero<<<1, 64, 0, stream>>>(ws + OFF_MKV, 16);                // zero pad for K=32 upper half
    k_prep_bf2<<<1344, 256, 0, stream>>>(conv_w, bf2);
    k_prep_bf<<<1104, 256, 0, stream>>>(o_w, bf);
    k_feed0<<<216, 256, 0, stream>>>(x, feedp);

    for (int t = 0; t < TSTEPS; ++t) {
        k_conv_lstm_mfma<<<dim3(24, 2, 16), 256, 0, stream>>>(feedp, hB, bf2, conv_b, c, hA);
        k_qkv<<<dim3(72, 10), 256, 0, stream>>>(hA, m, h_w, h_b, m_w, m_b, planes);
        k_attn<<<dim3(16, 72), 256, 0, stream>>>(planes, zbuf, z_w, z_b, Zp);
        k_conv_sa<<<dim3(24, 2, 16), 192, 0, stream>>>(Zp, hA, bf, o_b, m, hB);
        k_out_feed<<<288, 256, 0, stream>>>(hB, out_w, out_b, x, outp, feedp, t);
    }
    k_nino<<<1, 384, 0, stream>>>(outp, outp + (size_t)NB * TSTEPS * NCOUT * SS);
}